// Round 1
// 497.410 us; speedup vs baseline: 1.0489x; 1.0489x over previous
//
#include <hip/hip_runtime.h>

// ---------------------------------------------------------------------------
// SDGL gcn_module: out = W1*x + W2*(G1 x) + W3*(G2 x) + b
//   G1 = AL^2 + AS - AS*AL ; G2 = AL^3 + AS^2 - AS2*AL   (per-slice linear op)
// Pipeline:
//   1) cast AL,AS -> bf16 (natural + transposed)
//   2) transpose-cast x[b,c,w,t] -> xT[(b,c,t), w] bf16   (B^T operand)
//   3) 5 batched 1024^3 bf16 GEMMs -> G pieces; assemble G[2048,1024] bf16
//   4) main GEMM U[(g,n),(b,c,t)] = G @ xT^T   (M=2048,N=32768,K=1024)
//      -> NEW: 256x256-tile 8-wave pipelined schedule (T1+T2+T3+T4+T5):
//         BK=64, 4 phases/K-tile, counted s_waitcnt vmcnt(6) (never 0 in loop),
//         row-XOR LDS swizzle (pre-swizzled global src, linear global_load_lds
//         dest), s_setprio around MFMA cluster, XCD-aware block swizzle.
//   5) MFMA epilogue: out[j=(b,n,t), o] = H[j,0:96]·W~[o,:]^T + bias.
// ---------------------------------------------------------------------------

typedef __bf16 bf16x8 __attribute__((ext_vector_type(8)));
typedef float f32x4 __attribute__((ext_vector_type(4)));
typedef unsigned int u32x4 __attribute__((ext_vector_type(4)));
typedef unsigned int u32x2 __attribute__((ext_vector_type(2)));

__device__ __forceinline__ unsigned short f2bf(float f) {
  unsigned u = __builtin_bit_cast(unsigned, f);
  u += 0x7fffu + ((u >> 16) & 1u);           // round-to-nearest-even
  return (unsigned short)(u >> 16);
}
__device__ __forceinline__ float bf2f(unsigned short h) {
  unsigned u = ((unsigned)h) << 16;
  return __builtin_bit_cast(float, u);
}

// ---------------- workspace layout (bytes) ----------------
static constexpr size_t OFF_XT    = 0;                      // 32768*1024*2 = 64 MiB
static constexpr size_t OFF_U     = 67108864;               // 2048*32768*2 = 128 MiB
static constexpr size_t OFF_ALBF  = 201326592;              // each small mat 2 MiB
static constexpr size_t OFF_ALT   = OFF_ALBF  + 2097152;
static constexpr size_t OFF_ASBF  = OFF_ALT   + 2097152;
static constexpr size_t OFF_AST   = OFF_ASBF  + 2097152;
static constexpr size_t OFF_AL2   = OFF_AST   + 2097152;
static constexpr size_t OFF_AL2T  = OFF_AL2   + 2097152;
static constexpr size_t OFF_ASAL  = OFF_AL2T  + 2097152;
static constexpr size_t OFF_AS2   = OFF_ASAL  + 2097152;
static constexpr size_t OFF_AL3   = OFF_AS2   + 2097152;
static constexpr size_t OFF_AS2AL = OFF_AL3   + 2097152;
static constexpr size_t OFF_G     = OFF_AS2AL + 2097152;    // 2048*1024*2 = 4 MiB
// Wbf (32x96 bf16, 6 KiB) reuses OFF_ALBF after the pre-GEMMs retire ALbf.

// ---------------- simple fp32 -> bf16 cast ----------------
__global__ __launch_bounds__(256) void k_cast_bf16(const float* __restrict__ src,
                                                   unsigned short* __restrict__ dst,
                                                   int n4) {
  int i = blockIdx.x * 256 + threadIdx.x;
  if (i < n4) {
    float4 v = *((const float4*)src + i);
    unsigned lo = (unsigned)f2bf(v.x) | ((unsigned)f2bf(v.y) << 16);
    unsigned hi = (unsigned)f2bf(v.z) | ((unsigned)f2bf(v.w) << 16);
    u32x2 pk = {lo, hi};
    *(u32x2*)(dst + (size_t)i * 4) = pk;
  }
}

// ---------------- 64x64 tiled transpose + cast ----------------
__global__ __launch_bounds__(256) void k_transpose_cast(const float* __restrict__ src,
                                                        unsigned short* __restrict__ dst,
                                                        int R, int Cc) {
  __shared__ float Xs[64][65];
  const int tid = threadIdx.x;
  const size_t slice = (size_t)blockIdx.z * (size_t)R * (size_t)Cc;
  const float* s = src + slice;
  unsigned short* d = dst + slice;
  const int r0 = blockIdx.x * 64, c0 = blockIdx.y * 64;
  const int lrow = tid >> 4, lc4 = tid & 15;
#pragma unroll
  for (int rr = 0; rr < 4; rr++) {
    int row = rr * 16 + lrow;
    float4 v = *(const float4*)(s + (size_t)(r0 + row) * Cc + c0 + lc4 * 4);
    Xs[row][lc4 * 4 + 0] = v.x;
    Xs[row][lc4 * 4 + 1] = v.y;
    Xs[row][lc4 * 4 + 2] = v.z;
    Xs[row][lc4 * 4 + 3] = v.w;
  }
  __syncthreads();
  const int wc = tid & 7;
#pragma unroll
  for (int u = 0; u < 2; u++) {
    int t = u * 32 + (tid >> 3);
    unsigned v0 = (unsigned)f2bf(Xs[wc * 8 + 0][t]) | ((unsigned)f2bf(Xs[wc * 8 + 1][t]) << 16);
    unsigned v1 = (unsigned)f2bf(Xs[wc * 8 + 2][t]) | ((unsigned)f2bf(Xs[wc * 8 + 3][t]) << 16);
    unsigned v2 = (unsigned)f2bf(Xs[wc * 8 + 4][t]) | ((unsigned)f2bf(Xs[wc * 8 + 5][t]) << 16);
    unsigned v3 = (unsigned)f2bf(Xs[wc * 8 + 6][t]) | ((unsigned)f2bf(Xs[wc * 8 + 7][t]) << 16);
    u32x4 pk = {v0, v1, v2, v3};
    *(u32x4*)(d + (size_t)(c0 + t) * R + r0 + wc * 8) = pk;
  }
}

// ---------------- core 128x128 bf16 GEMM, C = A * Bt^T (pre-GEMMs) ----------
__device__ __forceinline__ void gemm128_bt(const unsigned short* __restrict__ A,
                                           const unsigned short* __restrict__ Bt,
                                           unsigned short* __restrict__ Cp,
                                           int K, size_t ldc, int m0, int n0) {
  __shared__ unsigned short As[128 * 32];
  __shared__ unsigned short Bs[128 * 32];
  const int tid = threadIdx.x;
  const int wave = tid >> 6, lane = tid & 63;
  const int lane15 = lane & 15, quad = lane >> 4;
  const int wm = wave & 1, wn = wave >> 1;
  const int srow = lane >> 2;
  const int schunk = (lane & 3) * 8;

  const unsigned short* gA0 = A + (size_t)(m0 + wave * 16 + srow) * K + schunk;
  const unsigned short* gA1 = A + (size_t)(m0 + 64 + wave * 16 + srow) * K + schunk;
  const unsigned short* gB0 = Bt + (size_t)(n0 + wave * 16 + srow) * K + schunk;
  const unsigned short* gB1 = Bt + (size_t)(n0 + 64 + wave * 16 + srow) * K + schunk;
  unsigned short* lA0 = As + (wave * 16) * 32;
  unsigned short* lA1 = As + (64 + wave * 16) * 32;
  unsigned short* lB0 = Bs + (wave * 16) * 32;
  unsigned short* lB1 = Bs + (64 + wave * 16) * 32;

  f32x4 acc[4][4];
#pragma unroll
  for (int i = 0; i < 4; i++)
#pragma unroll
    for (int j = 0; j < 4; j++) acc[i][j] = (f32x4){0.f, 0.f, 0.f, 0.f};

  const unsigned short* pa = As + (wm * 64 + lane15) * 32 + quad * 8;
  const unsigned short* pb = Bs + (wn * 64 + lane15) * 32 + quad * 8;

  for (int kb = 0; kb < K; kb += 32) {
    __syncthreads();
    __builtin_amdgcn_global_load_lds(
        (const __attribute__((address_space(1))) unsigned int*)(gA0 + kb),
        (__attribute__((address_space(3))) unsigned int*)lA0, 16, 0, 0);
    __builtin_amdgcn_global_load_lds(
        (const __attribute__((address_space(1))) unsigned int*)(gA1 + kb),
        (__attribute__((address_space(3))) unsigned int*)lA1, 16, 0, 0);
    __builtin_amdgcn_global_load_lds(
        (const __attribute__((address_space(1))) unsigned int*)(gB0 + kb),
        (__attribute__((address_space(3))) unsigned int*)lB0, 16, 0, 0);
    __builtin_amdgcn_global_load_lds(
        (const __attribute__((address_space(1))) unsigned int*)(gB1 + kb),
        (__attribute__((address_space(3))) unsigned int*)lB1, 16, 0, 0);
    __syncthreads();

    bf16x8 av[4], bv[4];
#pragma unroll
    for (int mt = 0; mt < 4; mt++) av[mt] = *(const bf16x8*)(pa + mt * 16 * 32);
#pragma unroll
    for (int nt = 0; nt < 4; nt++) bv[nt] = *(const bf16x8*)(pb + nt * 16 * 32);
#pragma unroll
    for (int mt = 0; mt < 4; mt++)
#pragma unroll
      for (int nt = 0; nt < 4; nt++)
        acc[mt][nt] = __builtin_amdgcn_mfma_f32_16x16x32_bf16(av[mt], bv[nt], acc[mt][nt], 0, 0, 0);
  }

#pragma unroll
  for (int mt = 0; mt < 4; mt++) {
#pragma unroll
    for (int nt = 0; nt < 4; nt++) {
      const int col = n0 + wn * 64 + nt * 16 + lane15;
#pragma unroll
      for (int r = 0; r < 4; r++) {
        const int row = m0 + wm * 64 + mt * 16 + quad * 4 + r;
        Cp[(size_t)row * ldc + col] = f2bf(acc[mt][nt][r]);
      }
    }
  }
}

// ---------------- G-precompute GEMMs (batched by z) ----------------
__global__ __launch_bounds__(256) void k_gemm_pre(char* ws, int stage) {
  const unsigned short* A;
  const unsigned short* Bt;
  unsigned short* Cp;
  const int z = blockIdx.z;
  unsigned short* ALbf = (unsigned short*)(ws + OFF_ALBF);
  unsigned short* ALt  = (unsigned short*)(ws + OFF_ALT);
  unsigned short* ASbf = (unsigned short*)(ws + OFF_ASBF);
  unsigned short* ASt  = (unsigned short*)(ws + OFF_AST);
  unsigned short* AL2  = (unsigned short*)(ws + OFF_AL2);
  unsigned short* AL2t = (unsigned short*)(ws + OFF_AL2T);
  unsigned short* ASAL = (unsigned short*)(ws + OFF_ASAL);
  unsigned short* AS2  = (unsigned short*)(ws + OFF_AS2);
  unsigned short* AL3  = (unsigned short*)(ws + OFF_AL3);
  unsigned short* AS2AL= (unsigned short*)(ws + OFF_AS2AL);
  if (stage == 0) {
    if (z == 0)      { A = ALbf; Bt = ALt;  Cp = AL2;  }   // AL^2
    else if (z == 1) { A = ALt;  Bt = ALbf; Cp = AL2t; }   // (AL^2)^T
    else if (z == 2) { A = ASbf; Bt = ALt;  Cp = ASAL; }   // AS*AL
    else             { A = ASbf; Bt = ASt;  Cp = AS2;  }   // AS^2
  } else {
    if (z == 0)      { A = ALbf; Bt = AL2t; Cp = AL3;  }   // AL^3
    else             { A = AS2;  Bt = ALt;  Cp = AS2AL;}   // AS^2*AL
  }
  gemm128_bt(A, Bt, Cp, 1024, 1024, blockIdx.y * 128, blockIdx.x * 128);
}

// ---------------- assemble G = [G1; G2] bf16 ----------------
__global__ __launch_bounds__(256) void k_assemble_G(const unsigned short* __restrict__ AL2,
                                                    const unsigned short* __restrict__ ASAL,
                                                    const float* __restrict__ ASf,
                                                    const unsigned short* __restrict__ AL3,
                                                    const unsigned short* __restrict__ AS2,
                                                    const unsigned short* __restrict__ AS2AL,
                                                    unsigned short* __restrict__ G) {
  int i = blockIdx.x * 256 + threadIdx.x;           // over 1024*1024
  float g1 = bf2f(AL2[i]) + ASf[i] - bf2f(ASAL[i]);
  G[i] = f2bf(g1);
  float g2 = bf2f(AL3[i]) + bf2f(AS2[i]) - bf2f(AS2AL[i]);
  G[1048576 + i] = f2bf(g2);
}

// ---------------- main GEMM: U = G @ xT^T  (256x256 tile, 8-phase pipeline) --
// M=2048, N=32768, K=1024 (NT = 16 K-tiles of BK=64).
// 512 thr = 8 waves (2M x 4N); per-wave C = 128x64 (acc[8][4] f32x4).
// LDS 128 KiB: [buf][A 256x64 | B 256x64] bf16, double-buffered per K-tile.
// Swizzle: phys_k = k ^ ((row&7)<<3) shorts; applied on ds_read addr AND on the
// global SOURCE of the (linear-dest) global_load_lds — both-sides involution.
// Schedule per K-tile u (phases p=0..3, one C-quadrant = m_rep{2p,2p+1} each):
//   p0: read 8 B-frags + 4 A-frags, stage A1(u+1)->alt ; p1: B0(u+2)->cur ;
//   p2: B1(u+2)->cur ; p3: A0(u+2)->cur, s_waitcnt vmcnt(6) (counted, never 0).
// Region-disjointness: B(u) reads retire at p0; A(u) band-p reads retire at p.
__global__ __launch_bounds__(512) void k_gemm_main8(const unsigned short* __restrict__ A,
                                                    const unsigned short* __restrict__ Bt,
                                                    unsigned short* __restrict__ C) {
  __shared__ unsigned short lds[65536];   // 128 KiB
  const int tid = threadIdx.x;
  const int wave = tid >> 6, lane = tid & 63;
  const int lane15 = lane & 15, quad = lane >> 4;
  const int wr = wave >> 2, wc = wave & 3;          // 2M x 4N

  // XCD-aware bijective swizzle (nwg=1024, 8 XCDs): groups of 8 consecutive
  // swz ids share one B-panel and span all 8 M-tiles.
  const int bid = blockIdx.x;
  const int swz = (bid & 7) * 128 + (bid >> 3);
  const int nx = swz >> 3, my = swz & 7;
  const int m0 = my * 256, n0 = nx * 256;

  // staging geometry: half-tile = 128 rows x 64 k; thread covers 16B chunk
  // c = issue*512 + tid ; source chunk pre-swizzled: kchunk ^= (row&7)
  const int srow = tid >> 3;                          // 0..63
  const int skc  = (((tid & 7) ^ (srow & 7)) << 3);   // shorts
  const int ldst0 = (tid & ~63) << 3;                 // shorts, wave-uniform

#define STAGE_HALF(gbase, rowbase, ldsptr, ktile)                                       \
  do {                                                                                  \
    const unsigned short* _g =                                                          \
        (gbase) + (size_t)((rowbase) + srow) * 1024 + (size_t)((ktile) * 64 + skc);     \
    __builtin_amdgcn_global_load_lds(                                                   \
        (const __attribute__((address_space(1))) unsigned int*)_g,                      \
        (__attribute__((address_space(3))) unsigned int*)((ldsptr) + ldst0), 16, 0, 0); \
    __builtin_amdgcn_global_load_lds(                                                   \
        (const __attribute__((address_space(1))) unsigned int*)(_g + 65536),            \
        (__attribute__((address_space(3))) unsigned int*)((ldsptr) + 4096 + ldst0),     \
        16, 0, 0);                                                                      \
  } while (0)

#define LOAD_AFR(p)                                                                     \
  bf16x8 afr[2][2];                                                                     \
  _Pragma("unroll") for (int mi = 0; mi < 2; mi++)                                      \
      _Pragma("unroll") for (int kk = 0; kk < 2; kk++)                                  \
          afr[mi][kk] = *(const bf16x8*)(pA + (2 * (p) + mi) * 1024 + aks[kk]);

#define MFMA_QUAD(p)                                                                    \
  _Pragma("unroll") for (int kk = 0; kk < 2; kk++)                                      \
      _Pragma("unroll") for (int mi = 0; mi < 2; mi++)                                  \
          _Pragma("unroll") for (int n = 0; n < 4; n++)                                 \
              acc[2 * (p) + mi][n] = __builtin_amdgcn_mfma_f32_16x16x32_bf16(           \
                  afr[mi][kk], bfr[n][kk], acc[2 * (p) + mi][n], 0, 0, 0);

#define PHASE_SYNC_PRE()                              \
  asm volatile("" ::: "memory");                      \
  __builtin_amdgcn_s_barrier();                       \
  asm volatile("s_waitcnt lgkmcnt(0)" ::: "memory");  \
  __builtin_amdgcn_sched_barrier(0);                  \
  __builtin_amdgcn_s_setprio(1);

#define PHASE_SYNC_POST()                             \
  __builtin_amdgcn_s_setprio(0);                      \
  asm volatile("" ::: "memory");                      \
  __builtin_amdgcn_s_barrier();

  unsigned short* Acur = lds;
  unsigned short* Bcur = lds + 16384;
  unsigned short* Aalt = lds + 32768;
  unsigned short* Balt = lds + 49152;

  f32x4 acc[8][4];
#pragma unroll
  for (int i = 0; i < 8; i++)
#pragma unroll
    for (int j = 0; j < 4; j++) acc[i][j] = (f32x4){0.f, 0.f, 0.f, 0.f};

  const int swz8 = (lane15 & 7) << 3;
  int aks[2];
  aks[0] = (quad << 3) ^ swz8;
  aks[1] = (32 | (quad << 3)) ^ swz8;

  // ---- prologue: tile0 fully + tile1 {B0,B1,A0}; vmcnt(6) => tile0 landed ----
  STAGE_HALF(Bt, n0,       Bcur,        0);
  STAGE_HALF(Bt, n0 + 128, Bcur + 8192, 0);
  STAGE_HALF(A,  m0,       Acur,        0);
  STAGE_HALF(A,  m0 + 128, Acur + 8192, 0);
  STAGE_HALF(Bt, n0,       Balt,        1);
  STAGE_HALF(Bt, n0 + 128, Balt + 8192, 1);
  STAGE_HALF(A,  m0,       Aalt,        1);
  asm volatile("s_waitcnt vmcnt(6)" ::: "memory");
  __builtin_amdgcn_s_barrier();

  // ---- main loop: tiles 0..13 with full staging ----
  for (int u = 0; u < 14; ++u) {
    const unsigned short* pA = Acur + (wr * 128 + lane15) * 64;
    const unsigned short* pB = Bcur + (wc * 64 + lane15) * 64;
    bf16x8 bfr[4][2];
    {   // phase 0: B frags (8) + A quad 0; stage A1(u+1) -> alt
#pragma unroll
      for (int n = 0; n < 4; n++)
#pragma unroll
        for (int kk = 0; kk < 2; kk++)
          bfr[n][kk] = *(const bf16x8*)(pB + n * 1024 + aks[kk]);
      LOAD_AFR(0)
      __builtin_amdgcn_sched_barrier(0);
      STAGE_HALF(A, m0 + 128, Aalt + 8192, u + 1);
      asm volatile("s_waitcnt lgkmcnt(8)" ::: "memory");
      PHASE_SYNC_PRE()
      MFMA_QUAD(0)
      PHASE_SYNC_POST()
    }
    {   // phase 1: stage B0(u+2) -> cur (B(u) reads retired at p0)
      LOAD_AFR(1)
      __builtin_amdgcn_sched_barrier(0);
      STAGE_HALF(Bt, n0, Bcur, u + 2);
      PHASE_SYNC_PRE()
      MFMA_QUAD(1)
      PHASE_SYNC_POST()
    }
    {   // phase 2: stage B1(u+2) -> cur
      LOAD_AFR(2)
      __builtin_amdgcn_sched_barrier(0);
      STAGE_HALF(Bt, n0 + 128, Bcur + 8192, u + 2);
      PHASE_SYNC_PRE()
      MFMA_QUAD(2)
      PHASE_SYNC_POST()
    }
    {   // phase 3: stage A0(u+2) -> cur ; counted vmcnt(6) => tile u+1 complete
      LOAD_AFR(3)
      __builtin_amdgcn_sched_barrier(0);
      STAGE_HALF(A, m0, Acur, u + 2);
      PHASE_SYNC_PRE()
      MFMA_QUAD(3)
      __builtin_amdgcn_s_setprio(0);
      asm volatile("s_waitcnt vmcnt(6)" ::: "memory");
      asm volatile("" ::: "memory");
      __builtin_amdgcn_s_barrier();
    }
    unsigned short* t;
    t = Acur; Acur = Aalt; Aalt = t;
    t = Bcur; Bcur = Balt; Balt = t;
  }

  // ---- tile 14: last stage (A1 of tile 15), then full drain ----
  {
    const unsigned short* pA = Acur + (wr * 128 + lane15) * 64;
    const unsigned short* pB = Bcur + (wc * 64 + lane15) * 64;
    bf16x8 bfr[4][2];
    {
#pragma unroll
      for (int n = 0; n < 4; n++)
#pragma unroll
        for (int kk = 0; kk < 2; kk++)
          bfr[n][kk] = *(const bf16x8*)(pB + n * 1024 + aks[kk]);
      LOAD_AFR(0)
      __builtin_amdgcn_sched_barrier(0);
      STAGE_HALF(A, m0 + 128, Aalt + 8192, 15);
      asm volatile("s_waitcnt lgkmcnt(8)" ::: "memory");
      PHASE_SYNC_PRE()
      MFMA_QUAD(0)
      PHASE_SYNC_POST()
    }
    { LOAD_AFR(1) PHASE_SYNC_PRE() MFMA_QUAD(1) PHASE_SYNC_POST() }
    { LOAD_AFR(2) PHASE_SYNC_PRE() MFMA_QUAD(2) PHASE_SYNC_POST() }
    {
      LOAD_AFR(3)
      PHASE_SYNC_PRE()
      MFMA_QUAD(3)
      __builtin_amdgcn_s_setprio(0);
      asm volatile("s_waitcnt vmcnt(0)" ::: "memory");
      asm volatile("" ::: "memory");
      __builtin_amdgcn_s_barrier();
    }
    unsigned short* t;
    t = Acur; Acur = Aalt; Aalt = t;
    t = Bcur; Bcur = Balt; Balt = t;
  }

  // ---- tile 15: pure compute, no staging / no barriers needed ----
  {
    const unsigned short* pA = Acur + (wr * 128 + lane15) * 64;
    const unsigned short* pB = Bcur + (wc * 64 + lane15) * 64;
    bf16x8 bfr[4][2];
#pragma unroll
    for (int n = 0; n < 4; n++)
#pragma unroll
      for (int kk = 0; kk < 2; kk++)
        bfr[n][kk] = *(const bf16x8*)(pB + n * 1024 + aks[kk]);
#pragma unroll
    for (int p = 0; p < 4; p++) {
      bf16x8 afr[2][2];
#pragma unroll
      for (int mi = 0; mi < 2; mi++)
#pragma unroll
        for (int kk = 0; kk < 2; kk++)
          afr[mi][kk] = *(const bf16x8*)(pA + (2 * p + mi) * 1024 + aks[kk]);
#pragma unroll
      for (int kk = 0; kk < 2; kk++)
#pragma unroll
        for (int mi = 0; mi < 2; mi++)
#pragma unroll
          for (int n = 0; n < 4; n++)
            acc[2 * p + mi][n] = __builtin_amdgcn_mfma_f32_16x16x32_bf16(
                afr[mi][kk], bfr[n][kk], acc[2 * p + mi][n], 0, 0, 0);
    }
  }

  // ---- C write: col=lane15-based (coalesced 32B segments), row=quad*4+r ----
#pragma unroll
  for (int mt = 0; mt < 8; mt++) {
    const int row = m0 + wr * 128 + mt * 16 + quad * 4;
#pragma unroll
    for (int n = 0; n < 4; n++) {
      const int col = n0 + wc * 64 + n * 16 + lane15;
#pragma unroll
      for (int r = 0; r < 4; r++)
        C[(size_t)(row + r) * 32768 + col] = f2bf(acc[mt][n][r]);
    }
  }
#undef STAGE_HALF
#undef LOAD_AFR
#undef MFMA_QUAD
#undef PHASE_SYNC_PRE
#undef PHASE_SYNC_POST
}

// ---------------- MFMA epilogue ----------------
__device__ __forceinline__ int swz_off(int j, int kc) {
  int s = (j ^ (j >> 3) ^ (j >> 6)) & 7;
  return (kc ^ s) << 3;
}

__global__ __launch_bounds__(256) void k_mix_mfma(const float* __restrict__ x,
                                                  const unsigned short* __restrict__ U,
                                                  const unsigned short* __restrict__ Wbf,
                                                  const float* __restrict__ bm,
                                                  float* __restrict__ out) {
  __shared__ unsigned short Hs[128 * 128];
  const int tid = threadIdx.x;
  const int b  = blockIdx.x >> 9;
  const int n0 = (blockIdx.x & 511) * 2;

  const float* xb = x + (size_t)b * 2097152 + (size_t)n0 * 64;
#pragma unroll
  for (int i = 0; i < 4; i++) {
    int q = tid + 256 * i;
    int p = q >> 4;
    int c = p >> 1, nn = p & 1;
    int t0 = (q & 15) * 4;
    float4 v = *(const float4*)(xb + (size_t)c * 65536 + nn * 64 + t0);
    int kc = c >> 3, wi = c & 7;
    float vv[4] = {v.x, v.y, v.z, v.w};
#pragma unroll
    for (int e = 0; e < 4; e++) {
      int j = nn * 64 + t0 + e;
      Hs[j * 128 + swz_off(j, kc) + wi] = f2bf(vv[e]);
    }
  }
#pragma unroll
  for (int i = 0; i < 4; i++) {
    int q = tid + 256 * i;
    int row = q >> 8;
    int g = row >> 1, nn = row & 1;
    int s8 = (q & 255) * 8;
    int c = s8 >> 6;
    const unsigned short* src =
        U + (size_t)(g * 1024 + n0 + nn) * 32768 + (size_t)b * 2048 + s8;
    u32x4 v = *(const u32x4*)src;
    int kc = 4 + g * 4 + (c >> 3), wi = c & 7;
#pragma unroll
    for (int e = 0; e < 4; e++) {
      int j0 = nn * 64 + (s8 & 63) + 2 * e;
      unsigned w = v[e];
      Hs[j0 * 128 + swz_off(j0, kc) + wi]           = (unsigned short)(w & 0xffffu);
      Hs[(j0 + 1) * 128 + swz_off(j0 + 1, kc) + wi] = (unsigned short)(w >> 16);
    }
  }
  __syncthreads();

  const int wave = tid >> 6, lane = tid & 63;
  const int lane15 = lane & 15, quad = lane >> 4;
  f32x4 acc[2][2];
#pragma unroll
  for (int jt = 0; jt < 2; jt++)
#pragma unroll
    for (int ot = 0; ot < 2; ot++) acc[jt][ot] = (f32x4){0.f, 0.f, 0.f, 0.f};

#pragma unroll
  for (int kchunk = 0; kchunk < 3; kchunk++) {
    bf16x8 bv[2];
#pragma unroll
    for (int ot = 0; ot < 2; ot++)
      bv[ot] = *(const bf16x8*)(Wbf + (ot * 16 + lane15) * 96 + kchunk * 32 + quad * 8);
#pragma unroll
    for (int jt = 0; jt < 2; jt++) {
      int j = wave * 32 + jt * 16 + lane15;
      bf16x8 av = *(const bf16x8*)(Hs + j * 128 + swz_off(j, kchunk * 4 + quad));
#pragma unroll
      for (int ot = 0; ot < 2; ot++)
        acc[jt][ot] = __builtin_amdgcn_mfma_f32_16x16x32_bf16(av, bv[ot], acc[jt][ot], 0, 0, 0);
    }
  }

#pragma unroll
  for (int jt = 0; jt < 2; jt++) {
#pragma unroll
    for (int ot = 0; ot < 2; ot++) {
      int col = ot * 16 + lane15;
      float bo = bm[col];
#pragma unroll
      for (int r = 0; r < 4; r++) {
        int j = wave * 32 + jt * 16 + quad * 4 + r;
        int nn = j >> 6, t = j & 63;
        out[(size_t)b * 2097152 + (size_t)col * 65536 + (size_t)(n0 + nn) * 64 + t] =
            acc[jt][ot][r] + bo;
      }
    }
  }
}

extern "C" void kernel_launch(void* const* d_in, const int* in_sizes, int n_in,
                              void* d_out, int out_size, void* d_ws, size_t ws_size,
                              hipStream_t stream) {
  const float* x  = (const float*)d_in[0];
  const float* AL = (const float*)d_in[1];
  const float* AS = (const float*)d_in[2];
  const float* W  = (const float*)d_in[3];
  const float* bm = (const float*)d_in[4];
  float* out = (float*)d_out;
  char* ws = (char*)d_ws;

  unsigned short* xT    = (unsigned short*)(ws + OFF_XT);
  unsigned short* U     = (unsigned short*)(ws + OFF_U);
  unsigned short* ALbf  = (unsigned short*)(ws + OFF_ALBF);
  unsigned short* ALt   = (unsigned short*)(ws + OFF_ALT);
  unsigned short* ASbf  = (unsigned short*)(ws + OFF_ASBF);
  unsigned short* ASt   = (unsigned short*)(ws + OFF_AST);
  unsigned short* AL2   = (unsigned short*)(ws + OFF_AL2);
  unsigned short* ASAL  = (unsigned short*)(ws + OFF_ASAL);
  unsigned short* AS2   = (unsigned short*)(ws + OFF_AS2);
  unsigned short* AL3   = (unsigned short*)(ws + OFF_AL3);
  unsigned short* AS2AL = (unsigned short*)(ws + OFF_AS2AL);
  unsigned short* Gm    = (unsigned short*)(ws + OFF_G);
  unsigned short* Wbf   = (unsigned short*)(ws + OFF_ALBF);  // reused after pre-GEMMs

  // 1) small casts + transposes (bf16 operands for precompute GEMMs)
  k_cast_bf16<<<1024, 256, 0, stream>>>(AL, ALbf, 262144);
  k_cast_bf16<<<1024, 256, 0, stream>>>(AS, ASbf, 262144);
  k_transpose_cast<<<dim3(16, 16, 1), 256, 0, stream>>>(AL, ALt, 1024, 1024);
  k_transpose_cast<<<dim3(16, 16, 1), 256, 0, stream>>>(AS, ASt, 1024, 1024);
  // 2) x[b,c,w,t] -> xT[(b,c,t), w]  (512 slices of 1024x64)
  k_transpose_cast<<<dim3(16, 1, 512), 256, 0, stream>>>(x, xT, 1024, 64);
  // 3) G pieces: {AL2, AL2t, ASAL, AS2} then {AL3, AS2AL}
  k_gemm_pre<<<dim3(8, 8, 4), 256, 0, stream>>>(ws, 0);
  k_gemm_pre<<<dim3(8, 8, 2), 256, 0, stream>>>(ws, 1);
  k_assemble_G<<<4096, 256, 0, stream>>>(AL2, ASAL, AS, AL3, AS2, AS2AL, Gm);
  // 3b) W -> bf16 (3072 floats = 768 float4), into retired ALbf slot
  k_cast_bf16<<<3, 256, 0, stream>>>(W, Wbf, 768);
  // 4) U[(g,n), (b,c,t)] = G @ xT^T   M=2048 N=32768 K=1024  (8-phase 256^2)
  k_gemm_main8<<<dim3(1024, 1, 1), 512, 0, stream>>>(Gm, xT, U);
  // 5) MFMA epilogue: out = H @ W~^T + bias  (8192 blocks of 128j x 32o)
  k_mix_mfma<<<dim3(8192, 1, 1), 256, 0, stream>>>(x, U, Wbf, bm, out);
}